// Round 1
// baseline (367.470 us; speedup 1.0000x reference)
//
#include <hip/hip_runtime.h>
#include <math.h>

#define TPB 256

__device__ __forceinline__ float jac(float tx0, float ty0, float tx1, float ty1, float ta,
                                     float px0, float py0, float px1, float py1, float pa) {
    float ltx = fmaxf(tx0, px0), lty = fmaxf(ty0, py0);
    float rbx = fminf(tx1, px1), rby = fminf(ty1, py1);
    float w = fmaxf(rbx - ltx, 0.0f), h = fmaxf(rby - lty, 0.0f);
    float inter = w * h;
    return inter / (ta + pa - inter);
}

// One block per batch image. Computes conf_t per prior, num_pos[b], and
// accumulates smooth-L1 loc loss + total positive count.
template <int ON>
__global__ __launch_bounds__(TPB) void match_kernel(
    const float* __restrict__ loc, const float* __restrict__ priors,
    const float* __restrict__ targets, int P, int O_rt,
    int* __restrict__ conf_t, int* __restrict__ num_pos,
    float* __restrict__ g_loss_l, int* __restrict__ g_N) {
    constexpr int OMAX = (ON > 0) ? ON : 64;
    const int O = (ON > 0) ? ON : O_rt;
    const int b = blockIdx.x, tid = threadIdx.x;

    __shared__ float s_tx0[OMAX], s_ty0[OMAX], s_tx1[OMAX], s_ty1[OMAX];
    __shared__ float s_lab[OMAX], s_area[OMAX];
    __shared__ int s_bp[OMAX];
    __shared__ float s_f[TPB];
    __shared__ int s_i[TPB];

    for (int o = tid; o < O; o += TPB) {
        const float* t = targets + ((size_t)b * O + o) * 5;
        float x0 = t[0], y0 = t[1], x1 = t[2], y1 = t[3];
        s_tx0[o] = x0; s_ty0[o] = y0; s_tx1[o] = x1; s_ty1[o] = y1;
        s_lab[o] = t[4];
        s_area[o] = (x1 - x0) * (y1 - y0);
    }
    __syncthreads();

    // Sweep 1: per-truth best prior (argmax over P, first-max wins).
    float bov[OMAX];
    int bidx[OMAX];
    for (int o = 0; o < O; ++o) { bov[o] = -1.0f; bidx[o] = 0x7FFFFFFF; }
    for (int p = tid; p < P; p += TPB) {
        float cx = priors[p * 4 + 0], cy = priors[p * 4 + 1];
        float pw = priors[p * 4 + 2], ph = priors[p * 4 + 3];
        float px0 = cx - pw * 0.5f, py0 = cy - ph * 0.5f;
        float px1 = cx + pw * 0.5f, py1 = cy + ph * 0.5f;
        float pa = (px1 - px0) * (py1 - py0);
        for (int o = 0; o < O; ++o) {
            float ov = jac(s_tx0[o], s_ty0[o], s_tx1[o], s_ty1[o], s_area[o],
                           px0, py0, px1, py1, pa);
            if (ov > bov[o]) { bov[o] = ov; bidx[o] = p; }  // strictly > keeps earliest p
        }
    }
    for (int o = 0; o < O; ++o) {
        s_f[tid] = bov[o]; s_i[tid] = bidx[o];
        __syncthreads();
        for (int s = TPB / 2; s > 0; s >>= 1) {
            if (tid < s) {
                float o2 = s_f[tid + s]; int i2 = s_i[tid + s];
                if (o2 > s_f[tid] || (o2 == s_f[tid] && i2 < s_i[tid])) {
                    s_f[tid] = o2; s_i[tid] = i2;
                }
            }
            __syncthreads();
        }
        if (tid == 0) s_bp[o] = s_i[0];
        __syncthreads();
    }

    // Sweep 2: per-prior best truth, override with forced matches (last-wins),
    // conf_t, loc encode, smooth-L1 over positives.
    float ll = 0.0f;
    int np = 0;
    for (int p = tid; p < P; p += TPB) {
        float cx = priors[p * 4 + 0], cy = priors[p * 4 + 1];
        float pw = priors[p * 4 + 2], ph = priors[p * 4 + 3];
        float px0 = cx - pw * 0.5f, py0 = cy - ph * 0.5f;
        float px1 = cx + pw * 0.5f, py1 = cy + ph * 0.5f;
        float pa = (px1 - px0) * (py1 - py0);
        float bto = -1.0f;
        int bti = 0;
        for (int o = 0; o < O; ++o) {
            float ov = jac(s_tx0[o], s_ty0[o], s_tx1[o], s_ty1[o], s_area[o],
                           px0, py0, px1, py1, pa);
            if (ov > bto) { bto = ov; bti = o; }  // first-max over o
        }
        for (int o = 0; o < O; ++o) {
            if (s_bp[o] == p) { bto = 2.0f; bti = o; }  // last o wins, matches scatter
        }
        int c = (bto < 0.5f) ? 0 : ((int)s_lab[bti] + 1);
        conf_t[(size_t)b * P + p] = c;
        if (c > 0) {
            ++np;
            float mx0 = s_tx0[bti], my0 = s_ty0[bti], mx1 = s_tx1[bti], my1 = s_ty1[bti];
            float g0 = ((mx0 + mx1) * 0.5f - cx) / (0.1f * pw);
            float g1 = ((my0 + my1) * 0.5f - cy) / (0.1f * ph);
            float g2 = logf(fmaxf((mx1 - mx0) / pw, 1e-8f)) / 0.2f;
            float g3 = logf(fmaxf((my1 - my0) / ph, 1e-8f)) / 0.2f;
            float gt4[4] = {g0, g1, g2, g3};
            const float* ld = loc + ((size_t)b * P + p) * 4;
#pragma unroll
            for (int j = 0; j < 4; ++j) {
                float d = ld[j] - gt4[j];
                float ad = fabsf(d);
                ll += (ad < 1.0f) ? 0.5f * d * d : (ad - 0.5f);
            }
        }
    }
    __syncthreads();
    s_f[tid] = ll; s_i[tid] = np;
    __syncthreads();
    for (int s = TPB / 2; s > 0; s >>= 1) {
        if (tid < s) { s_f[tid] += s_f[tid + s]; s_i[tid] += s_i[tid + s]; }
        __syncthreads();
    }
    if (tid == 0) {
        num_pos[b] = s_i[0];
        atomicAdd(g_loss_l, s_f[0]);
        atomicAdd(g_N, s_i[0]);
    }
}

// Per-prior conf loss: lse - gathered. mined = pos ? 0 : lc; positives'
// lc accumulated per-batch.
__global__ __launch_bounds__(TPB) void conf_kernel(
    const float* __restrict__ conf, const int* __restrict__ conf_t,
    float* __restrict__ mined, float* __restrict__ sum_pos_c,
    int BP, int P, int C) {
    int i = blockIdx.x * TPB + threadIdx.x;
    if (i >= BP) return;
    const float* row = conf + (size_t)i * C;
    float m = row[0];
    for (int j = 1; j < C; ++j) m = fmaxf(m, row[j]);
    float s = 0.0f;
    for (int j = 0; j < C; ++j) s += expf(row[j] - m);
    float lse = m + logf(s);
    int c = conf_t[i];
    float lc = lse - row[c];  // >= 0 always (s >= 1)
    bool pos = c > 0;
    mined[i] = pos ? 0.0f : lc;
    if (pos) atomicAdd(&sum_pos_c[i / P], lc);
}

// One block per batch: radix-select k-th largest of mined (all >= 0 so float
// bits are order-monotonic), then sum of top-k = sum_{>T} + (k - cnt_gt) * T.
// Tie membership is value-identical so the sum is exact regardless of which
// tied indices the reference's stable argsort picks.
__global__ __launch_bounds__(TPB) void select_kernel(
    const float* __restrict__ mined, const int* __restrict__ num_pos,
    const float* __restrict__ sum_pos_c, float* __restrict__ g_loss_c,
    int P, int ratio) {
    const int b = blockIdx.x, tid = threadIdx.x;
    const float* v = mined + (size_t)b * P;
    int npos = num_pos[b];
    int k = min(ratio * npos, P - npos);
    if (k <= 0) {
        if (tid == 0) atomicAdd(g_loss_c, sum_pos_c[b]);
        return;
    }
    __shared__ int s_hist[256];
    __shared__ unsigned s_bsel;
    __shared__ int s_krn;
    unsigned prefix = 0u;
    int kr = k;
    for (int pass = 0; pass < 4; ++pass) {
        int shift = 24 - 8 * pass;
        unsigned mask = (pass == 0) ? 0u : (0xFFFFFFFFu << (32 - 8 * pass));
        s_hist[tid] = 0;
        __syncthreads();
        for (int p = tid; p < P; p += TPB) {
            unsigned u = __float_as_uint(v[p]);
            if ((u & mask) == prefix) atomicAdd(&s_hist[(u >> shift) & 0xFF], 1);
        }
        __syncthreads();
        if (tid == 0) {
            int acc = 0;
            for (int i = 255; i >= 0; --i) {
                acc += s_hist[i];
                if (acc >= kr) {
                    s_bsel = (unsigned)i;
                    s_krn = kr - (acc - s_hist[i]);
                    break;
                }
            }
        }
        __syncthreads();
        prefix |= s_bsel << shift;
        kr = s_krn;
        __syncthreads();
    }
    float T = __uint_as_float(prefix);  // exact k-th largest value
    float lsum = 0.0f;
    int lcnt = 0;
    for (int p = tid; p < P; p += TPB) {
        float x = v[p];
        if (x > T) { lsum += x; ++lcnt; }
    }
    __shared__ float s_rs[TPB];
    __shared__ int s_rc[TPB];
    s_rs[tid] = lsum; s_rc[tid] = lcnt;
    __syncthreads();
    for (int s = TPB / 2; s > 0; s >>= 1) {
        if (tid < s) { s_rs[tid] += s_rs[tid + s]; s_rc[tid] += s_rc[tid + s]; }
        __syncthreads();
    }
    if (tid == 0) {
        float lc = sum_pos_c[b] + s_rs[0] + (float)(k - s_rc[0]) * T;
        atomicAdd(g_loss_c, lc);
    }
}

__global__ void finalize_kernel(const float* __restrict__ g_loss_l,
                                const float* __restrict__ g_loss_c,
                                const int* __restrict__ g_N,
                                float* __restrict__ out) {
    float N = (float)(*g_N);
    out[0] = *g_loss_l / N;
    out[1] = *g_loss_c / N;
}

extern "C" void kernel_launch(void* const* d_in, const int* in_sizes, int n_in,
                              void* d_out, int out_size, void* d_ws, size_t ws_size,
                              hipStream_t stream) {
    const float* loc = (const float*)d_in[0];
    const float* conf = (const float*)d_in[1];
    const float* priors = (const float*)d_in[2];
    const float* targets = (const float*)d_in[3];

    const int P = in_sizes[2] / 4;
    const int B = in_sizes[0] / (P * 4);
    const int C = in_sizes[1] / (in_sizes[0] / 4);  // conf / (B*P)
    const int O = in_sizes[3] / (B * 5);
    const size_t BP = (size_t)B * P;

    // ws layout
    float* mined = (float*)d_ws;                 // BP floats
    int* conf_t = (int*)(mined + BP);            // BP ints
    float* sum_pos_c = (float*)(conf_t + BP);    // B floats   (zeroed)
    int* num_pos = (int*)(sum_pos_c + B);        // B ints     (zeroed, fully overwritten)
    float* g_loss_l = (float*)(num_pos + B);     // 1 float    (zeroed)
    float* g_loss_c = g_loss_l + 1;              // 1 float    (zeroed)
    int* g_N = (int*)(g_loss_c + 1);             // 1 int      (zeroed)

    hipMemsetAsync(sum_pos_c, 0, (size_t)(2 * B + 3) * sizeof(float), stream);

    if (O == 8) {
        match_kernel<8><<<B, TPB, 0, stream>>>(loc, priors, targets, P, O, conf_t,
                                               num_pos, g_loss_l, g_N);
    } else {
        match_kernel<0><<<B, TPB, 0, stream>>>(loc, priors, targets, P, O, conf_t,
                                               num_pos, g_loss_l, g_N);
    }

    int conf_blocks = (int)((BP + TPB - 1) / TPB);
    conf_kernel<<<conf_blocks, TPB, 0, stream>>>(conf, conf_t, mined, sum_pos_c,
                                                 (int)BP, P, C);

    select_kernel<<<B, TPB, 0, stream>>>(mined, num_pos, sum_pos_c, g_loss_c, P, 3);

    finalize_kernel<<<1, 1, 0, stream>>>(g_loss_l, g_loss_c, g_N, (float*)d_out);
}

// Round 2
// 288.359 us; speedup vs baseline: 1.2743x; 1.2743x over previous
//
#include <hip/hip_runtime.h>
#include <math.h>

#define TPB 256

__device__ __forceinline__ float jac(float tx0, float ty0, float tx1, float ty1, float ta,
                                     float px0, float py0, float px1, float py1, float pa) {
    float ltx = fmaxf(tx0, px0), lty = fmaxf(ty0, py0);
    float rbx = fminf(tx1, px1), rby = fminf(ty1, py1);
    float w = fmaxf(rbx - ltx, 0.0f), h = fmaxf(rby - lty, 0.0f);
    float inter = w * h;
    return inter / (ta + pa - inter);
}

// Stage 1 of matching: per-truth best prior (argmax over P, first-max wins),
// parallel over (batch, prior-chunk). Partial results combined with a packed
// u64 atomicMax: key = (ov_bits<<32) | (0xFFFFFFFF - p). ov >= 0 so float
// bits are order-monotone; ~p prefers the SMALLEST p on ties, matching the
// reference's first-max argmax.
template <int ON>
__global__ __launch_bounds__(TPB) void match1_kernel(
    const float* __restrict__ priors, const float* __restrict__ targets,
    int P, int O_rt, int S, int CH,
    unsigned long long* __restrict__ keys) {
    constexpr int OMAX = (ON > 0) ? ON : 64;
    const int O = (ON > 0) ? ON : O_rt;
    const int b = blockIdx.x / S;
    const int chunk = blockIdx.x % S;
    const int p0 = chunk * CH;
    const int p1 = min(p0 + CH, P);
    const int tid = threadIdx.x;

    __shared__ float s_tx0[OMAX], s_ty0[OMAX], s_tx1[OMAX], s_ty1[OMAX], s_area[OMAX];
    for (int o = tid; o < O; o += TPB) {
        const float* t = targets + ((size_t)b * O + o) * 5;
        float x0 = t[0], y0 = t[1], x1 = t[2], y1 = t[3];
        s_tx0[o] = x0; s_ty0[o] = y0; s_tx1[o] = x1; s_ty1[o] = y1;
        s_area[o] = (x1 - x0) * (y1 - y0);
    }
    __syncthreads();

    float bov[OMAX];
    int bidx[OMAX];
    for (int o = 0; o < O; ++o) { bov[o] = -1.0f; bidx[o] = 0x7FFFFFFF; }
    for (int p = p0 + tid; p < p1; p += TPB) {
        float4 pr = ((const float4*)priors)[p];
        float px0 = pr.x - pr.z * 0.5f, py0 = pr.y - pr.w * 0.5f;
        float px1 = pr.x + pr.z * 0.5f, py1 = pr.y + pr.w * 0.5f;
        float pa = (px1 - px0) * (py1 - py0);
        for (int o = 0; o < O; ++o) {
            float ov = jac(s_tx0[o], s_ty0[o], s_tx1[o], s_ty1[o], s_area[o],
                           px0, py0, px1, py1, pa);
            if (ov > bov[o]) { bov[o] = ov; bidx[o] = p; }  // strictly > keeps earliest p
        }
    }

    __shared__ float s_f[TPB];
    __shared__ int s_i[TPB];
    for (int o = 0; o < O; ++o) {
        s_f[tid] = bov[o]; s_i[tid] = bidx[o];
        __syncthreads();
        for (int s = TPB / 2; s > 0; s >>= 1) {
            if (tid < s) {
                float o2 = s_f[tid + s]; int i2 = s_i[tid + s];
                if (o2 > s_f[tid] || (o2 == s_f[tid] && i2 < s_i[tid])) {
                    s_f[tid] = o2; s_i[tid] = i2;
                }
            }
            __syncthreads();
        }
        if (tid == 0 && s_i[0] != 0x7FFFFFFF) {
            unsigned long long key =
                ((unsigned long long)__float_as_uint(s_f[0]) << 32) |
                (unsigned long long)(0xFFFFFFFFu - (unsigned)s_i[0]);
            atomicMax(&keys[(size_t)b * O + o], key);
        }
        __syncthreads();
    }
}

// Stage 2: per-prior best truth + forced-match override (last o wins, matching
// the reference scatter), conf_t, loc encode, smooth-L1 over positives.
template <int ON>
__global__ __launch_bounds__(TPB) void match2_kernel(
    const float* __restrict__ loc, const float* __restrict__ priors,
    const float* __restrict__ targets, int P, int O_rt, int S, int CH,
    const unsigned long long* __restrict__ keys,
    int* __restrict__ conf_t, int* __restrict__ num_pos,
    float* __restrict__ g_loss_l, int* __restrict__ g_N) {
    constexpr int OMAX = (ON > 0) ? ON : 64;
    const int O = (ON > 0) ? ON : O_rt;
    const int b = blockIdx.x / S;
    const int chunk = blockIdx.x % S;
    const int p0 = chunk * CH;
    const int p1 = min(p0 + CH, P);
    const int tid = threadIdx.x;

    __shared__ float s_tx0[OMAX], s_ty0[OMAX], s_tx1[OMAX], s_ty1[OMAX];
    __shared__ float s_lab[OMAX], s_area[OMAX];
    __shared__ int s_bp[OMAX];
    for (int o = tid; o < O; o += TPB) {
        const float* t = targets + ((size_t)b * O + o) * 5;
        float x0 = t[0], y0 = t[1], x1 = t[2], y1 = t[3];
        s_tx0[o] = x0; s_ty0[o] = y0; s_tx1[o] = x1; s_ty1[o] = y1;
        s_lab[o] = t[4];
        s_area[o] = (x1 - x0) * (y1 - y0);
        s_bp[o] = (int)(0xFFFFFFFFu - (unsigned)(keys[(size_t)b * O + o] & 0xFFFFFFFFull));
    }
    __syncthreads();

    float ll = 0.0f;
    int np = 0;
    for (int p = p0 + tid; p < p1; p += TPB) {
        float4 pr = ((const float4*)priors)[p];
        float cx = pr.x, cy = pr.y, pw = pr.z, ph = pr.w;
        float px0 = cx - pw * 0.5f, py0 = cy - ph * 0.5f;
        float px1 = cx + pw * 0.5f, py1 = cy + ph * 0.5f;
        float pa = (px1 - px0) * (py1 - py0);
        float bto = -1.0f;
        int bti = 0;
        for (int o = 0; o < O; ++o) {
            float ov = jac(s_tx0[o], s_ty0[o], s_tx1[o], s_ty1[o], s_area[o],
                           px0, py0, px1, py1, pa);
            if (ov > bto) { bto = ov; bti = o; }  // first-max over o
        }
        for (int o = 0; o < O; ++o) {
            if (s_bp[o] == p) { bto = 2.0f; bti = o; }  // last o wins (ref scatter)
        }
        int c = (bto < 0.5f) ? 0 : ((int)s_lab[bti] + 1);
        conf_t[(size_t)b * P + p] = c;
        if (c > 0) {
            ++np;
            float mx0 = s_tx0[bti], my0 = s_ty0[bti], mx1 = s_tx1[bti], my1 = s_ty1[bti];
            float g0 = ((mx0 + mx1) * 0.5f - cx) / (0.1f * pw);
            float g1 = ((my0 + my1) * 0.5f - cy) / (0.1f * ph);
            float g2 = logf(fmaxf((mx1 - mx0) / pw, 1e-8f)) / 0.2f;
            float g3 = logf(fmaxf((my1 - my0) / ph, 1e-8f)) / 0.2f;
            float4 ld = ((const float4*)loc)[(size_t)b * P + p];
            float gt4[4] = {g0, g1, g2, g3};
            float lv[4] = {ld.x, ld.y, ld.z, ld.w};
#pragma unroll
            for (int j = 0; j < 4; ++j) {
                float d = lv[j] - gt4[j];
                float ad = fabsf(d);
                ll += (ad < 1.0f) ? 0.5f * d * d : (ad - 0.5f);
            }
        }
    }

    __shared__ float s_f[TPB];
    __shared__ int s_i[TPB];
    s_f[tid] = ll; s_i[tid] = np;
    __syncthreads();
    for (int s = TPB / 2; s > 0; s >>= 1) {
        if (tid < s) { s_f[tid] += s_f[tid + s]; s_i[tid] += s_i[tid + s]; }
        __syncthreads();
    }
    if (tid == 0) {
        atomicAdd(&num_pos[b], s_i[0]);
        atomicAdd(g_loss_l, s_f[0]);
        atomicAdd(g_N, s_i[0]);
    }
}

// Per-prior conf loss: lse - gathered. LDS-staged so global reads are fully
// coalesced float4 (fixes the 7x HBM over-fetch of the scalar-row version).
template <int CN>
__global__ __launch_bounds__(TPB) void conf_kernel(
    const float* __restrict__ conf, const int* __restrict__ conf_t,
    float* __restrict__ mined, float* __restrict__ sum_pos_c,
    int BP, int P, int C_rt) {
    const int C = (CN > 0) ? CN : C_rt;
    const int base = blockIdx.x * TPB;
    const int n = min(TPB, BP - base);
    const int tid = threadIdx.x;
    __shared__ float s_rows[TPB * ((CN > 0) ? CN : 32)];

    const float* g = conf + (size_t)base * C;
    const int nf = n * C;
    const int nf4 = nf >> 2;
    const float4* g4 = (const float4*)g;
    float4* s4 = (float4*)s_rows;
    for (int i = tid; i < nf4; i += TPB) s4[i] = g4[i];
    for (int i = (nf4 << 2) + tid; i < nf; i += TPB) s_rows[i] = g[i];
    __syncthreads();

    if (tid >= n) return;
    const float* row = s_rows + tid * C;  // stride 21 floats: 2-way bank alias, free
    float m = row[0];
    for (int j = 1; j < C; ++j) m = fmaxf(m, row[j]);
    float s = 0.0f;
    for (int j = 0; j < C; ++j) s += expf(row[j] - m);
    float lse = m + logf(s);
    const int i = base + tid;
    int c = conf_t[i];
    float lc = lse - row[c];  // >= 0 always (s >= 1)
    bool pos = c > 0;
    mined[i] = pos ? 0.0f : lc;
    if (pos) atomicAdd(&sum_pos_c[i / P], lc);
}

// One block per batch: radix-select k-th largest of mined (all >= 0 so float
// bits are order-monotone), then sum of top-k = sum_{>T} + (k - cnt_gt) * T.
// Tie membership is value-identical so the sum is exact regardless of which
// tied indices the reference's stable argsort picks.
__global__ __launch_bounds__(TPB) void select_kernel(
    const float* __restrict__ mined, const int* __restrict__ num_pos,
    const float* __restrict__ sum_pos_c, float* __restrict__ g_loss_c,
    int P, int ratio) {
    const int b = blockIdx.x, tid = threadIdx.x;
    const float* v = mined + (size_t)b * P;
    int npos = num_pos[b];
    int k = min(ratio * npos, P - npos);
    if (k <= 0) {
        if (tid == 0) atomicAdd(g_loss_c, sum_pos_c[b]);
        return;
    }
    __shared__ int s_hist[256];
    __shared__ unsigned s_bsel;
    __shared__ int s_krn;
    unsigned prefix = 0u;
    int kr = k;
    for (int pass = 0; pass < 4; ++pass) {
        int shift = 24 - 8 * pass;
        unsigned mask = (pass == 0) ? 0u : (0xFFFFFFFFu << (32 - 8 * pass));
        s_hist[tid] = 0;
        __syncthreads();
        for (int p = tid; p < P; p += TPB) {
            unsigned u = __float_as_uint(v[p]);
            if ((u & mask) == prefix) atomicAdd(&s_hist[(u >> shift) & 0xFF], 1);
        }
        __syncthreads();
        if (tid == 0) {
            int acc = 0;
            for (int i = 255; i >= 0; --i) {
                acc += s_hist[i];
                if (acc >= kr) {
                    s_bsel = (unsigned)i;
                    s_krn = kr - (acc - s_hist[i]);
                    break;
                }
            }
        }
        __syncthreads();
        prefix |= s_bsel << shift;
        kr = s_krn;
        __syncthreads();
    }
    float T = __uint_as_float(prefix);  // exact k-th largest value
    float lsum = 0.0f;
    int lcnt = 0;
    for (int p = tid; p < P; p += TPB) {
        float x = v[p];
        if (x > T) { lsum += x; ++lcnt; }
    }
    __shared__ float s_rs[TPB];
    __shared__ int s_rc[TPB];
    s_rs[tid] = lsum; s_rc[tid] = lcnt;
    __syncthreads();
    for (int s = TPB / 2; s > 0; s >>= 1) {
        if (tid < s) { s_rs[tid] += s_rs[tid + s]; s_rc[tid] += s_rc[tid + s]; }
        __syncthreads();
    }
    if (tid == 0) {
        float lc = sum_pos_c[b] + s_rs[0] + (float)(k - s_rc[0]) * T;
        atomicAdd(g_loss_c, lc);
    }
}

__global__ void finalize_kernel(const float* __restrict__ g_loss_l,
                                const float* __restrict__ g_loss_c,
                                const int* __restrict__ g_N,
                                float* __restrict__ out) {
    float N = (float)(*g_N);
    out[0] = *g_loss_l / N;
    out[1] = *g_loss_c / N;
}

extern "C" void kernel_launch(void* const* d_in, const int* in_sizes, int n_in,
                              void* d_out, int out_size, void* d_ws, size_t ws_size,
                              hipStream_t stream) {
    const float* loc = (const float*)d_in[0];
    const float* conf = (const float*)d_in[1];
    const float* priors = (const float*)d_in[2];
    const float* targets = (const float*)d_in[3];

    const int P = in_sizes[2] / 4;
    const int B = in_sizes[0] / (P * 4);
    const int C = in_sizes[1] / (in_sizes[0] / 4);  // conf / (B*P)
    const int O = in_sizes[3] / (B * 5);
    const size_t BP = (size_t)B * P;

    // ws layout: [mined BP f32][conf_t BP i32][keys B*O u64][sum_pos_c B f32]
    //            [num_pos B i32][g_loss_l][g_loss_c][g_N]  (zero region = keys..end)
    float* mined = (float*)d_ws;
    int* conf_t = (int*)(mined + BP);
    unsigned long long* keys = (unsigned long long*)(conf_t + BP);  // 8B-aligned: 8*BP bytes in
    float* sum_pos_c = (float*)(keys + (size_t)B * O);
    int* num_pos = (int*)(sum_pos_c + B);
    float* g_loss_l = (float*)(num_pos + B);
    float* g_loss_c = g_loss_l + 1;
    int* g_N = (int*)(g_loss_c + 1);

    size_t zero_bytes = (size_t)B * O * 8 + (size_t)B * 8 + 12;
    hipMemsetAsync(keys, 0, zero_bytes, stream);

    const int CH = 1024;  // priors per chunk
    const int S = (P + CH - 1) / CH;

    if (O == 8) {
        match1_kernel<8><<<B * S, TPB, 0, stream>>>(priors, targets, P, O, S, CH, keys);
        match2_kernel<8><<<B * S, TPB, 0, stream>>>(loc, priors, targets, P, O, S, CH,
                                                    keys, conf_t, num_pos, g_loss_l, g_N);
    } else {
        match1_kernel<0><<<B * S, TPB, 0, stream>>>(priors, targets, P, O, S, CH, keys);
        match2_kernel<0><<<B * S, TPB, 0, stream>>>(loc, priors, targets, P, O, S, CH,
                                                    keys, conf_t, num_pos, g_loss_l, g_N);
    }

    int conf_blocks = (int)((BP + TPB - 1) / TPB);
    if (C == 21) {
        conf_kernel<21><<<conf_blocks, TPB, 0, stream>>>(conf, conf_t, mined, sum_pos_c,
                                                         (int)BP, P, C);
    } else {
        conf_kernel<0><<<conf_blocks, TPB, 0, stream>>>(conf, conf_t, mined, sum_pos_c,
                                                        (int)BP, P, C);
    }

    select_kernel<<<B, TPB, 0, stream>>>(mined, num_pos, sum_pos_c, g_loss_c, P, 3);

    finalize_kernel<<<1, 1, 0, stream>>>(g_loss_l, g_loss_c, g_N, (float*)d_out);
}

// Round 3
// 232.451 us; speedup vs baseline: 1.5809x; 1.2405x over previous
//
#include <hip/hip_runtime.h>
#include <math.h>

#define TPB 256

__device__ __forceinline__ float jac(float tx0, float ty0, float tx1, float ty1, float ta,
                                     float px0, float py0, float px1, float py1, float pa) {
    float ltx = fmaxf(tx0, px0), lty = fmaxf(ty0, py0);
    float rbx = fminf(tx1, px1), rby = fminf(ty1, py1);
    float w = fmaxf(rbx - ltx, 0.0f), h = fmaxf(rby - lty, 0.0f);
    float inter = w * h;
    return inter / (ta + pa - inter);
}

// One block per batch image; both matching sweeps fused. NO global atomics:
// num_pos[b] / part_ll[b] are plain per-block stores.
template <int ON>
__global__ __launch_bounds__(TPB) void match_kernel(
    const float* __restrict__ loc, const float* __restrict__ priors,
    const float* __restrict__ targets, int P, int O_rt,
    int* __restrict__ conf_t, int* __restrict__ num_pos,
    float* __restrict__ part_ll) {
    constexpr int OMAX = (ON > 0) ? ON : 64;
    const int O = (ON > 0) ? ON : O_rt;
    const int b = blockIdx.x, tid = threadIdx.x;

    __shared__ float s_tx0[OMAX], s_ty0[OMAX], s_tx1[OMAX], s_ty1[OMAX];
    __shared__ float s_lab[OMAX], s_area[OMAX];
    __shared__ int s_bp[OMAX];
    __shared__ float s_f[TPB];
    __shared__ int s_i[TPB];

    for (int o = tid; o < O; o += TPB) {
        const float* t = targets + ((size_t)b * O + o) * 5;
        float x0 = t[0], y0 = t[1], x1 = t[2], y1 = t[3];
        s_tx0[o] = x0; s_ty0[o] = y0; s_tx1[o] = x1; s_ty1[o] = y1;
        s_lab[o] = t[4];
        s_area[o] = (x1 - x0) * (y1 - y0);
    }
    __syncthreads();

    // Sweep 1: per-truth best prior (argmax over P, first-max wins).
    float bov[OMAX];
    int bidx[OMAX];
    for (int o = 0; o < O; ++o) { bov[o] = -1.0f; bidx[o] = 0x7FFFFFFF; }
    for (int p = tid; p < P; p += TPB) {
        float4 pr = ((const float4*)priors)[p];
        float px0 = pr.x - pr.z * 0.5f, py0 = pr.y - pr.w * 0.5f;
        float px1 = pr.x + pr.z * 0.5f, py1 = pr.y + pr.w * 0.5f;
        float pa = (px1 - px0) * (py1 - py0);
        for (int o = 0; o < O; ++o) {
            float ov = jac(s_tx0[o], s_ty0[o], s_tx1[o], s_ty1[o], s_area[o],
                           px0, py0, px1, py1, pa);
            if (ov > bov[o]) { bov[o] = ov; bidx[o] = p; }  // strictly > keeps earliest p
        }
    }
    for (int o = 0; o < O; ++o) {
        s_f[tid] = bov[o]; s_i[tid] = bidx[o];
        __syncthreads();
        for (int s = TPB / 2; s > 0; s >>= 1) {
            if (tid < s) {
                float o2 = s_f[tid + s]; int i2 = s_i[tid + s];
                if (o2 > s_f[tid] || (o2 == s_f[tid] && i2 < s_i[tid])) {
                    s_f[tid] = o2; s_i[tid] = i2;
                }
            }
            __syncthreads();
        }
        if (tid == 0) s_bp[o] = s_i[0];
        __syncthreads();
    }

    // Sweep 2: per-prior best truth + forced-match override (last o wins,
    // matching the reference scatter), conf_t, loc encode, smooth-L1.
    float ll = 0.0f;
    int np = 0;
    for (int p = tid; p < P; p += TPB) {
        float4 pr = ((const float4*)priors)[p];
        float cx = pr.x, cy = pr.y, pw = pr.z, ph = pr.w;
        float px0 = cx - pw * 0.5f, py0 = cy - ph * 0.5f;
        float px1 = cx + pw * 0.5f, py1 = cy + ph * 0.5f;
        float pa = (px1 - px0) * (py1 - py0);
        float bto = -1.0f;
        int bti = 0;
        for (int o = 0; o < O; ++o) {
            float ov = jac(s_tx0[o], s_ty0[o], s_tx1[o], s_ty1[o], s_area[o],
                           px0, py0, px1, py1, pa);
            if (ov > bto) { bto = ov; bti = o; }  // first-max over o
        }
        for (int o = 0; o < O; ++o) {
            if (s_bp[o] == p) { bto = 2.0f; bti = o; }  // last o wins (ref scatter)
        }
        int c = (bto < 0.5f) ? 0 : ((int)s_lab[bti] + 1);
        conf_t[(size_t)b * P + p] = c;
        if (c > 0) {
            ++np;
            float mx0 = s_tx0[bti], my0 = s_ty0[bti], mx1 = s_tx1[bti], my1 = s_ty1[bti];
            float g0 = ((mx0 + mx1) * 0.5f - cx) / (0.1f * pw);
            float g1 = ((my0 + my1) * 0.5f - cy) / (0.1f * ph);
            float g2 = logf(fmaxf((mx1 - mx0) / pw, 1e-8f)) / 0.2f;
            float g3 = logf(fmaxf((my1 - my0) / ph, 1e-8f)) / 0.2f;
            float4 ld = ((const float4*)loc)[(size_t)b * P + p];
            float gt4[4] = {g0, g1, g2, g3};
            float lv[4] = {ld.x, ld.y, ld.z, ld.w};
#pragma unroll
            for (int j = 0; j < 4; ++j) {
                float d = lv[j] - gt4[j];
                float ad = fabsf(d);
                ll += (ad < 1.0f) ? 0.5f * d * d : (ad - 0.5f);
            }
        }
    }
    __syncthreads();
    s_f[tid] = ll; s_i[tid] = np;
    __syncthreads();
    for (int s = TPB / 2; s > 0; s >>= 1) {
        if (tid < s) { s_f[tid] += s_f[tid + s]; s_i[tid] += s_i[tid + s]; }
        __syncthreads();
    }
    if (tid == 0) {
        num_pos[b] = s_i[0];   // plain store — single block per batch
        part_ll[b] = s_f[0];
    }
}

// Per-prior conf loss, batch-aligned blocks (grid = B*CB). LDS-staged
// coalesced float4 reads; per-block positive-conf partial sum via plain
// store to part_pc[block] — NO global atomics.
template <int CN>
__global__ __launch_bounds__(TPB) void conf_kernel(
    const float* __restrict__ conf, const int* __restrict__ conf_t,
    float* __restrict__ mined, float* __restrict__ part_pc,
    int P, int CB, int C_rt) {
    const int C = (CN > 0) ? CN : C_rt;
    const int b = blockIdx.x / CB;
    const int chunk = blockIdx.x % CB;
    const int r0 = chunk * TPB;
    const int n = min(TPB, P - r0);
    const int tid = threadIdx.x;
    __shared__ float s_rows[TPB * ((CN > 0) ? CN : 32)];

    const float* g = conf + ((size_t)b * P + r0) * C;
    const int nf = n * C;
    if ((((size_t)g) & 15) == 0) {
        const int nf4 = nf >> 2;
        const float4* g4 = (const float4*)g;
        float4* s4 = (float4*)s_rows;
        for (int i = tid; i < nf4; i += TPB) s4[i] = g4[i];
        for (int i = (nf4 << 2) + tid; i < nf; i += TPB) s_rows[i] = g[i];
    } else {
        for (int i = tid; i < nf; i += TPB) s_rows[i] = g[i];
    }
    __syncthreads();

    float posc = 0.0f;
    if (tid < n) {
        const float* row = s_rows + tid * C;  // stride-21 LDS: 2-way alias, free
        float m = row[0];
        for (int j = 1; j < C; ++j) m = fmaxf(m, row[j]);
        float s = 0.0f;
        for (int j = 0; j < C; ++j) s += expf(row[j] - m);
        float lse = m + logf(s);
        const size_t i = (size_t)b * P + r0 + tid;
        int c = conf_t[i];
        float lc = lse - row[c];  // >= 0 always (s >= 1)
        bool pos = c > 0;
        mined[i] = pos ? 0.0f : lc;
        if (pos) posc = lc;
    }
    __syncthreads();
    s_rows[tid] = posc;  // reuse LDS as reduction buffer
    __syncthreads();
    for (int s = TPB / 2; s > 0; s >>= 1) {
        if (tid < s) s_rows[tid] += s_rows[tid + s];
        __syncthreads();
    }
    if (tid == 0) part_pc[blockIdx.x] = s_rows[0];
}

// One block per batch: sum pos-conf partials, radix-select k-th largest of
// mined (all >= 0 so float bits are order-monotone), then
// sum(top-k) = sum_{>T} + (k - cnt_gt) * T. Tie membership is
// value-identical so the sum is exact regardless of which tied indices the
// reference's stable argsort picks. Result plain-stored to lc_batch[b].
__global__ __launch_bounds__(TPB) void select_kernel(
    const float* __restrict__ mined, const int* __restrict__ num_pos,
    const float* __restrict__ part_pc, float* __restrict__ lc_batch,
    int P, int CB, int ratio) {
    const int b = blockIdx.x, tid = threadIdx.x;
    const float* v = mined + (size_t)b * P;

    __shared__ float s_rs[TPB];
    __shared__ int s_rc[TPB];
    float ps = 0.0f;
    for (int i = tid; i < CB; i += TPB) ps += part_pc[b * CB + i];
    s_rs[tid] = ps;
    __syncthreads();
    for (int s = TPB / 2; s > 0; s >>= 1) {
        if (tid < s) s_rs[tid] += s_rs[tid + s];
        __syncthreads();
    }
    const float sum_pos = s_rs[0];
    __syncthreads();

    const int npos = num_pos[b];
    const int k = min(ratio * npos, P - npos);
    if (k <= 0) {
        if (tid == 0) lc_batch[b] = sum_pos;
        return;
    }

    __shared__ int s_hist[256];
    __shared__ unsigned s_bsel;
    __shared__ int s_krn;
    unsigned prefix = 0u;
    int kr = k;
    for (int pass = 0; pass < 4; ++pass) {
        int shift = 24 - 8 * pass;
        unsigned mask = (pass == 0) ? 0u : (0xFFFFFFFFu << (32 - 8 * pass));
        s_hist[tid] = 0;
        __syncthreads();
        for (int p = tid; p < P; p += TPB) {
            unsigned u = __float_as_uint(v[p]);
            if ((u & mask) == prefix) atomicAdd(&s_hist[(u >> shift) & 0xFF], 1);
        }
        __syncthreads();
        if (tid == 0) {
            int acc = 0;
            for (int i = 255; i >= 0; --i) {
                acc += s_hist[i];
                if (acc >= kr) {
                    s_bsel = (unsigned)i;
                    s_krn = kr - (acc - s_hist[i]);
                    break;
                }
            }
        }
        __syncthreads();
        prefix |= s_bsel << shift;
        kr = s_krn;
        __syncthreads();
    }
    float T = __uint_as_float(prefix);  // exact k-th largest value
    float lsum = 0.0f;
    int lcnt = 0;
    for (int p = tid; p < P; p += TPB) {
        float x = v[p];
        if (x > T) { lsum += x; ++lcnt; }
    }
    s_rs[tid] = lsum; s_rc[tid] = lcnt;
    __syncthreads();
    for (int s = TPB / 2; s > 0; s >>= 1) {
        if (tid < s) { s_rs[tid] += s_rs[tid + s]; s_rc[tid] += s_rc[tid + s]; }
        __syncthreads();
    }
    if (tid == 0) lc_batch[b] = sum_pos + s_rs[0] + (float)(k - s_rc[0]) * T;
}

__global__ __launch_bounds__(TPB) void finalize_kernel(
    const float* __restrict__ part_ll, const int* __restrict__ num_pos,
    const float* __restrict__ lc_batch, int B, float* __restrict__ out) {
    const int tid = threadIdx.x;
    __shared__ float s_l[TPB], s_c[TPB];
    __shared__ int s_n[TPB];
    float l = 0.0f, c = 0.0f;
    int n = 0;
    for (int i = tid; i < B; i += TPB) {
        l += part_ll[i];
        c += lc_batch[i];
        n += num_pos[i];
    }
    s_l[tid] = l; s_c[tid] = c; s_n[tid] = n;
    __syncthreads();
    for (int s = TPB / 2; s > 0; s >>= 1) {
        if (tid < s) {
            s_l[tid] += s_l[tid + s];
            s_c[tid] += s_c[tid + s];
            s_n[tid] += s_n[tid + s];
        }
        __syncthreads();
    }
    if (tid == 0) {
        float N = (float)s_n[0];
        out[0] = s_l[0] / N;
        out[1] = s_c[0] / N;
    }
}

extern "C" void kernel_launch(void* const* d_in, const int* in_sizes, int n_in,
                              void* d_out, int out_size, void* d_ws, size_t ws_size,
                              hipStream_t stream) {
    const float* loc = (const float*)d_in[0];
    const float* conf = (const float*)d_in[1];
    const float* priors = (const float*)d_in[2];
    const float* targets = (const float*)d_in[3];

    const int P = in_sizes[2] / 4;
    const int B = in_sizes[0] / (P * 4);
    const int C = in_sizes[1] / (in_sizes[0] / 4);  // conf / (B*P)
    const int O = in_sizes[3] / (B * 5);
    const size_t BP = (size_t)B * P;
    const int CB = (P + TPB - 1) / TPB;  // conf chunks per batch

    // ws layout (everything fully written before read — no memset, no atomics):
    float* mined = (float*)d_ws;               // BP f32
    int* conf_t = (int*)(mined + BP);          // BP i32
    int* num_pos = (int*)(conf_t + BP);        // B  i32
    float* part_ll = (float*)(num_pos + B);    // B  f32
    float* lc_batch = part_ll + B;             // B  f32
    float* part_pc = lc_batch + B;             // B*CB f32

    if (O == 8) {
        match_kernel<8><<<B, TPB, 0, stream>>>(loc, priors, targets, P, O,
                                               conf_t, num_pos, part_ll);
    } else {
        match_kernel<0><<<B, TPB, 0, stream>>>(loc, priors, targets, P, O,
                                               conf_t, num_pos, part_ll);
    }

    if (C == 21) {
        conf_kernel<21><<<B * CB, TPB, 0, stream>>>(conf, conf_t, mined, part_pc,
                                                    P, CB, C);
    } else {
        conf_kernel<0><<<B * CB, TPB, 0, stream>>>(conf, conf_t, mined, part_pc,
                                                   P, CB, C);
    }

    select_kernel<<<B, TPB, 0, stream>>>(mined, num_pos, part_pc, lc_batch, P, CB, 3);

    finalize_kernel<<<1, TPB, 0, stream>>>(part_ll, num_pos, lc_batch, B, (float*)d_out);
}

// Round 4
// 149.778 us; speedup vs baseline: 2.4534x; 1.5520x over previous
//
#include <hip/hip_runtime.h>
#include <math.h>

#define TPB 256
#define CHP 512  // priors per match1 chunk

__device__ __forceinline__ float jac(float tx0, float ty0, float tx1, float ty1, float ta,
                                     float px0, float py0, float px1, float py1, float pa) {
    float ltx = fmaxf(tx0, px0), lty = fmaxf(ty0, py0);
    float rbx = fminf(tx1, px1), rby = fminf(ty1, py1);
    float w = fmaxf(rbx - ltx, 0.0f), h = fmaxf(rby - lty, 0.0f);
    float inter = w * h;
    return inter / (ta + pa - inter);
}

// Stage 1: per-(b,o) partial best-prior over a 512-prior chunk.
// Packed key = (ov_bits<<32) | (0xFFFFFFFF - p): ov >= 0 so float bits are
// order-monotone; ~p prefers the SMALLEST p on ties (reference first-max
// argmax). Key 0 = "no prior" and loses to any real prior. Plain stores.
template <int ON>
__global__ __launch_bounds__(TPB) void match1_kernel(
    const float* __restrict__ priors, const float* __restrict__ targets,
    int P, int O_rt, int S1, unsigned long long* __restrict__ pkeys) {
    constexpr int OMAX = (ON > 0) ? ON : 64;
    const int O = (ON > 0) ? ON : O_rt;
    const int b = blockIdx.x / S1;
    const int chunk = blockIdx.x % S1;
    const int p0 = chunk * CHP;
    const int p1 = min(p0 + CHP, P);
    const int tid = threadIdx.x;
    const int lane = tid & 63, wv = tid >> 6;

    __shared__ float s_tx0[OMAX], s_ty0[OMAX], s_tx1[OMAX], s_ty1[OMAX], s_area[OMAX];
    __shared__ unsigned long long s_wk[TPB / 64][OMAX];
    for (int o = tid; o < O; o += TPB) {
        const float* t = targets + ((size_t)b * O + o) * 5;
        float x0 = t[0], y0 = t[1], x1 = t[2], y1 = t[3];
        s_tx0[o] = x0; s_ty0[o] = y0; s_tx1[o] = x1; s_ty1[o] = y1;
        s_area[o] = (x1 - x0) * (y1 - y0);
    }
    __syncthreads();

    unsigned long long k[OMAX];
    for (int o = 0; o < O; ++o) k[o] = 0ull;
    for (int p = p0 + tid; p < p1; p += TPB) {
        float4 pr = ((const float4*)priors)[p];
        float px0 = pr.x - pr.z * 0.5f, py0 = pr.y - pr.w * 0.5f;
        float px1 = pr.x + pr.z * 0.5f, py1 = pr.y + pr.w * 0.5f;
        float pa = (px1 - px0) * (py1 - py0);
        for (int o = 0; o < O; ++o) {
            float ov = jac(s_tx0[o], s_ty0[o], s_tx1[o], s_ty1[o], s_area[o],
                           px0, py0, px1, py1, pa);
            unsigned long long kk =
                ((unsigned long long)__float_as_uint(ov) << 32) |
                (unsigned long long)(0xFFFFFFFFu - (unsigned)p);
            if (kk > k[o]) k[o] = kk;
        }
    }
    for (int o = 0; o < O; ++o) {
        unsigned long long kk = k[o];
        for (int off = 32; off > 0; off >>= 1) {
            unsigned long long other = __shfl_down(kk, off, 64);
            if (other > kk) kk = other;
        }
        if (lane == 0) s_wk[wv][o] = kk;
    }
    __syncthreads();
    if (tid < O) {
        unsigned long long kk = s_wk[0][tid];
        for (int w = 1; w < TPB / 64; ++w)
            if (s_wk[w][tid] > kk) kk = s_wk[w][tid];
        pkeys[((size_t)b * O + tid) * S1 + chunk] = kk;
    }
}

// Stage 2 fused with conf loss. Grid B*CB, 256 priors per block.
// Reduces the S1 partial keys in LDS, does the per-prior sweep + forced
// override (last o wins, matching the reference scatter), then computes
// lse - gathered from LDS-staged conf rows. Plain per-block partial stores.
template <int ON, int CN>
__global__ __launch_bounds__(TPB) void match2_conf_kernel(
    const float* __restrict__ loc, const float* __restrict__ priors,
    const float* __restrict__ targets, const float* __restrict__ conf,
    const unsigned long long* __restrict__ pkeys,
    int P, int O_rt, int C_rt, int S1, int CB,
    float* __restrict__ mined, float* __restrict__ part_ll,
    float* __restrict__ part_pc, int* __restrict__ part_np) {
    constexpr int OMAX = (ON > 0) ? ON : 64;
    const int O = (ON > 0) ? ON : O_rt;
    const int C = (CN > 0) ? CN : C_rt;
    const int b = blockIdx.x / CB;
    const int chunk = blockIdx.x % CB;
    const int r0 = chunk * TPB;
    const int n = min(TPB, P - r0);
    const int tid = threadIdx.x;

    __shared__ float s_rows[TPB * ((CN > 0) ? CN : 32)];
    __shared__ float s_tx0[OMAX], s_ty0[OMAX], s_tx1[OMAX], s_ty1[OMAX];
    __shared__ float s_lab[OMAX], s_area[OMAX];
    __shared__ unsigned long long s_keys[OMAX];
    __shared__ int s_bp[OMAX];
    __shared__ float s_f[TPB], s_g[TPB];
    __shared__ int s_i[TPB];

    for (int o = tid; o < O; o += TPB) {
        const float* t = targets + ((size_t)b * O + o) * 5;
        float x0 = t[0], y0 = t[1], x1 = t[2], y1 = t[3];
        s_tx0[o] = x0; s_ty0[o] = y0; s_tx1[o] = x1; s_ty1[o] = y1;
        s_lab[o] = t[4];
        s_area[o] = (x1 - x0) * (y1 - y0);
        s_keys[o] = 0ull;
    }
    __syncthreads();

    // reduce partial keys (block-local LDS atomics — no contention issue)
    if (tid < O * S1) {
        int o = tid / S1, s = tid % S1;
        atomicMax(&s_keys[o], pkeys[((size_t)b * O + o) * S1 + s]);
    }
    // stage conf rows, coalesced float4
    {
        const float* g = conf + ((size_t)b * P + r0) * C;
        const int nf = n * C;
        if ((((size_t)g) & 15) == 0) {
            const int nf4 = nf >> 2;
            const float4* g4 = (const float4*)g;
            float4* s4 = (float4*)s_rows;
            for (int i = tid; i < nf4; i += TPB) s4[i] = g4[i];
            for (int i = (nf4 << 2) + tid; i < nf; i += TPB) s_rows[i] = g[i];
        } else {
            for (int i = tid; i < nf; i += TPB) s_rows[i] = g[i];
        }
    }
    __syncthreads();
    if (tid < O)
        s_bp[tid] = (int)(0xFFFFFFFFu - (unsigned)(s_keys[tid] & 0xFFFFFFFFull));
    __syncthreads();

    float ll = 0.0f, posc = 0.0f;
    int np = 0;
    if (tid < n) {
        const int p = r0 + tid;
        float4 pr = ((const float4*)priors)[p];
        float cx = pr.x, cy = pr.y, pw = pr.z, ph = pr.w;
        float px0 = cx - pw * 0.5f, py0 = cy - ph * 0.5f;
        float px1 = cx + pw * 0.5f, py1 = cy + ph * 0.5f;
        float pa = (px1 - px0) * (py1 - py0);
        float bto = -1.0f;
        int bti = 0;
        for (int o = 0; o < O; ++o) {
            float ov = jac(s_tx0[o], s_ty0[o], s_tx1[o], s_ty1[o], s_area[o],
                           px0, py0, px1, py1, pa);
            if (ov > bto) { bto = ov; bti = o; }  // first-max over o
        }
        for (int o = 0; o < O; ++o) {
            if (s_bp[o] == p) { bto = 2.0f; bti = o; }  // last o wins (ref scatter)
        }
        int c = (bto < 0.5f) ? 0 : ((int)s_lab[bti] + 1);

        const float* row = s_rows + tid * C;  // stride-21 LDS: 2-way alias, free
        float m = row[0];
        for (int j = 1; j < C; ++j) m = fmaxf(m, row[j]);
        float s = 0.0f;
        for (int j = 0; j < C; ++j) s += expf(row[j] - m);
        float lse = m + logf(s);
        float lc = lse - row[c];  // >= 0 always (s >= 1)
        bool pos = c > 0;
        mined[(size_t)b * P + p] = pos ? 0.0f : lc;
        if (pos) {
            posc = lc;
            np = 1;
            float mx0 = s_tx0[bti], my0 = s_ty0[bti], mx1 = s_tx1[bti], my1 = s_ty1[bti];
            float g0 = ((mx0 + mx1) * 0.5f - cx) / (0.1f * pw);
            float g1 = ((my0 + my1) * 0.5f - cy) / (0.1f * ph);
            float g2 = logf(fmaxf((mx1 - mx0) / pw, 1e-8f)) / 0.2f;
            float g3 = logf(fmaxf((my1 - my0) / ph, 1e-8f)) / 0.2f;
            float4 ld = ((const float4*)loc)[(size_t)b * P + p];
            float gt4[4] = {g0, g1, g2, g3};
            float lv[4] = {ld.x, ld.y, ld.z, ld.w};
#pragma unroll
            for (int j = 0; j < 4; ++j) {
                float d = lv[j] - gt4[j];
                float ad = fabsf(d);
                ll += (ad < 1.0f) ? 0.5f * d * d : (ad - 0.5f);
            }
        }
    }
    __syncthreads();
    s_f[tid] = ll; s_g[tid] = posc; s_i[tid] = np;
    __syncthreads();
    for (int s = TPB / 2; s > 0; s >>= 1) {
        if (tid < s) {
            s_f[tid] += s_f[tid + s];
            s_g[tid] += s_g[tid + s];
            s_i[tid] += s_i[tid + s];
        }
        __syncthreads();
    }
    if (tid == 0) {
        part_ll[blockIdx.x] = s_f[0];
        part_pc[blockIdx.x] = s_g[0];
        part_np[blockIdx.x] = s_i[0];
    }
}

// One block per batch: reduce per-chunk partials, radix-select k-th largest
// of mined (all >= 0, bit-monotone), sum(top-k) = sum_{>T} + (k-cnt)*T.
// Per-wave histograms avoid cross-wave LDS atomic serialization; bin pick
// via parallel suffix sums. Plain stores only.
__global__ __launch_bounds__(TPB) void select_kernel(
    const float* __restrict__ mined, const float* __restrict__ part_ll,
    const float* __restrict__ part_pc, const int* __restrict__ part_np,
    float* __restrict__ ll_batch, float* __restrict__ lc_batch,
    int* __restrict__ np_batch, int P, int CB, int ratio) {
    const int b = blockIdx.x, tid = threadIdx.x;
    const int wv = tid >> 6;
    const float* v = mined + (size_t)b * P;

    __shared__ float s_rs[TPB], s_rg[TPB];
    __shared__ int s_rc[TPB];
    float pll = 0.0f, ppc = 0.0f;
    int pnp = 0;
    for (int i = tid; i < CB; i += TPB) {
        pll += part_ll[b * CB + i];
        ppc += part_pc[b * CB + i];
        pnp += part_np[b * CB + i];
    }
    s_rs[tid] = pll; s_rg[tid] = ppc; s_rc[tid] = pnp;
    __syncthreads();
    for (int s = TPB / 2; s > 0; s >>= 1) {
        if (tid < s) {
            s_rs[tid] += s_rs[tid + s];
            s_rg[tid] += s_rg[tid + s];
            s_rc[tid] += s_rc[tid + s];
        }
        __syncthreads();
    }
    const float ll_sum = s_rs[0];
    const float sum_pos = s_rg[0];
    const int npos = s_rc[0];
    __syncthreads();

    const int k = min(ratio * npos, P - npos);
    if (tid == 0) {
        ll_batch[b] = ll_sum;
        np_batch[b] = npos;
    }
    if (k <= 0) {
        if (tid == 0) lc_batch[b] = sum_pos;
        return;
    }

    __shared__ int s_hist[(TPB / 64) * 256];
    __shared__ int s_histR[256];
    __shared__ unsigned s_bsel;
    __shared__ int s_krn;
    unsigned prefix = 0u;
    int kr = k;
    for (int pass = 0; pass < 4; ++pass) {
        int shift = 24 - 8 * pass;
        unsigned mask = (pass == 0) ? 0u : (0xFFFFFFFFu << (32 - 8 * pass));
        for (int i = tid; i < (TPB / 64) * 256; i += TPB) s_hist[i] = 0;
        __syncthreads();
        for (int p = tid; p < P; p += TPB) {
            unsigned u = __float_as_uint(v[p]);
            if ((u & mask) == prefix)
                atomicAdd(&s_hist[wv * 256 + ((u >> shift) & 0xFF)], 1);
        }
        __syncthreads();
        if (tid < 256) {
            int h = 0;
            for (int w = 0; w < TPB / 64; ++w) h += s_hist[w * 256 + tid];
            s_histR[tid] = h;
        }
        __syncthreads();
        if (tid < 256) {
            int sgt = 0;
            for (int i = tid + 1; i < 256; ++i) sgt += s_histR[i];
            int sge = sgt + s_histR[tid];
            if (sge >= kr && sgt < kr) {  // exactly one tid satisfies
                s_bsel = (unsigned)tid;
                s_krn = kr - sgt;
            }
        }
        __syncthreads();
        prefix |= s_bsel << shift;
        kr = s_krn;
        __syncthreads();
    }
    float T = __uint_as_float(prefix);  // exact k-th largest value
    float lsum = 0.0f;
    int lcnt = 0;
    for (int p = tid; p < P; p += TPB) {
        float x = v[p];
        if (x > T) { lsum += x; ++lcnt; }
    }
    s_rs[tid] = lsum; s_rc[tid] = lcnt;
    __syncthreads();
    for (int s = TPB / 2; s > 0; s >>= 1) {
        if (tid < s) { s_rs[tid] += s_rs[tid + s]; s_rc[tid] += s_rc[tid + s]; }
        __syncthreads();
    }
    if (tid == 0) lc_batch[b] = sum_pos + s_rs[0] + (float)(k - s_rc[0]) * T;
}

__global__ __launch_bounds__(TPB) void finalize_kernel(
    const float* __restrict__ ll_batch, const int* __restrict__ np_batch,
    const float* __restrict__ lc_batch, int B, float* __restrict__ out) {
    const int tid = threadIdx.x;
    __shared__ float s_l[TPB], s_c[TPB];
    __shared__ int s_n[TPB];
    float l = 0.0f, c = 0.0f;
    int n = 0;
    for (int i = tid; i < B; i += TPB) {
        l += ll_batch[i];
        c += lc_batch[i];
        n += np_batch[i];
    }
    s_l[tid] = l; s_c[tid] = c; s_n[tid] = n;
    __syncthreads();
    for (int s = TPB / 2; s > 0; s >>= 1) {
        if (tid < s) {
            s_l[tid] += s_l[tid + s];
            s_c[tid] += s_c[tid + s];
            s_n[tid] += s_n[tid + s];
        }
        __syncthreads();
    }
    if (tid == 0) {
        float N = (float)s_n[0];
        out[0] = s_l[0] / N;
        out[1] = s_c[0] / N;
    }
}

extern "C" void kernel_launch(void* const* d_in, const int* in_sizes, int n_in,
                              void* d_out, int out_size, void* d_ws, size_t ws_size,
                              hipStream_t stream) {
    const float* loc = (const float*)d_in[0];
    const float* conf = (const float*)d_in[1];
    const float* priors = (const float*)d_in[2];
    const float* targets = (const float*)d_in[3];

    const int P = in_sizes[2] / 4;
    const int B = in_sizes[0] / (P * 4);
    const int C = in_sizes[1] / (in_sizes[0] / 4);  // conf / (B*P)
    const int O = in_sizes[3] / (B * 5);
    const size_t BP = (size_t)B * P;
    const int S1 = (P + CHP - 1) / CHP;   // match1 chunks per batch
    const int CB = (P + TPB - 1) / TPB;   // match2/conf chunks per batch

    // ws layout (8B-aligned first; everything fully written before read):
    unsigned long long* pkeys = (unsigned long long*)d_ws;  // B*O*S1 u64
    float* mined = (float*)(pkeys + (size_t)B * O * S1);    // BP f32
    float* part_ll = mined + BP;                            // B*CB f32
    float* part_pc = part_ll + (size_t)B * CB;              // B*CB f32
    int* part_np = (int*)(part_pc + (size_t)B * CB);        // B*CB i32
    float* ll_batch = (float*)(part_np + (size_t)B * CB);   // B f32
    float* lc_batch = ll_batch + B;                         // B f32
    int* np_batch = (int*)(lc_batch + B);                   // B i32

    if (O == 8) {
        match1_kernel<8><<<B * S1, TPB, 0, stream>>>(priors, targets, P, O, S1, pkeys);
        if (C == 21) {
            match2_conf_kernel<8, 21><<<B * CB, TPB, 0, stream>>>(
                loc, priors, targets, conf, pkeys, P, O, C, S1, CB,
                mined, part_ll, part_pc, part_np);
        } else {
            match2_conf_kernel<8, 0><<<B * CB, TPB, 0, stream>>>(
                loc, priors, targets, conf, pkeys, P, O, C, S1, CB,
                mined, part_ll, part_pc, part_np);
        }
    } else {
        match1_kernel<0><<<B * S1, TPB, 0, stream>>>(priors, targets, P, O, S1, pkeys);
        match2_conf_kernel<0, 0><<<B * CB, TPB, 0, stream>>>(
            loc, priors, targets, conf, pkeys, P, O, C, S1, CB,
            mined, part_ll, part_pc, part_np);
    }

    select_kernel<<<B, TPB, 0, stream>>>(mined, part_ll, part_pc, part_np,
                                         ll_batch, lc_batch, np_batch, P, CB, 3);

    finalize_kernel<<<1, TPB, 0, stream>>>(ll_batch, np_batch, lc_batch, B,
                                           (float*)d_out);
}

// Round 5
// 137.566 us; speedup vs baseline: 2.6712x; 1.0888x over previous
//
#include <hip/hip_runtime.h>
#include <math.h>

#define TPB 256
#define CHP 512      // priors per match1 chunk
#define TPBS 1024    // select block size
#define RCAP 12      // register cache capacity (supports P <= 12*1024)

__device__ __forceinline__ float jac(float tx0, float ty0, float tx1, float ty1, float ta,
                                     float px0, float py0, float px1, float py1, float pa) {
    float ltx = fmaxf(tx0, px0), lty = fmaxf(ty0, py0);
    float rbx = fminf(tx1, px1), rby = fminf(ty1, py1);
    float w = fmaxf(rbx - ltx, 0.0f), h = fmaxf(rby - lty, 0.0f);
    float inter = w * h;
    return inter / (ta + pa - inter);
}

// Stage 1: per-(b,o) partial best-prior over a 512-prior chunk.
// Packed key = (ov_bits<<32) | (0xFFFFFFFF - p): ov >= 0 so float bits are
// order-monotone; ~p prefers the SMALLEST p on ties (reference first-max
// argmax). Key 0 = "no prior" and loses to any real prior. Plain stores.
template <int ON>
__global__ __launch_bounds__(TPB) void match1_kernel(
    const float* __restrict__ priors, const float* __restrict__ targets,
    int P, int O_rt, int S1, unsigned long long* __restrict__ pkeys) {
    constexpr int OMAX = (ON > 0) ? ON : 64;
    const int O = (ON > 0) ? ON : O_rt;
    const int b = blockIdx.x / S1;
    const int chunk = blockIdx.x % S1;
    const int p0 = chunk * CHP;
    const int p1 = min(p0 + CHP, P);
    const int tid = threadIdx.x;
    const int lane = tid & 63, wv = tid >> 6;

    __shared__ float s_tx0[OMAX], s_ty0[OMAX], s_tx1[OMAX], s_ty1[OMAX], s_area[OMAX];
    __shared__ unsigned long long s_wk[TPB / 64][OMAX];
    for (int o = tid; o < O; o += TPB) {
        const float* t = targets + ((size_t)b * O + o) * 5;
        float x0 = t[0], y0 = t[1], x1 = t[2], y1 = t[3];
        s_tx0[o] = x0; s_ty0[o] = y0; s_tx1[o] = x1; s_ty1[o] = y1;
        s_area[o] = (x1 - x0) * (y1 - y0);
    }
    __syncthreads();

    unsigned long long k[OMAX];
    for (int o = 0; o < O; ++o) k[o] = 0ull;
    for (int p = p0 + tid; p < p1; p += TPB) {
        float4 pr = ((const float4*)priors)[p];
        float px0 = pr.x - pr.z * 0.5f, py0 = pr.y - pr.w * 0.5f;
        float px1 = pr.x + pr.z * 0.5f, py1 = pr.y + pr.w * 0.5f;
        float pa = (px1 - px0) * (py1 - py0);
        for (int o = 0; o < O; ++o) {
            float ov = jac(s_tx0[o], s_ty0[o], s_tx1[o], s_ty1[o], s_area[o],
                           px0, py0, px1, py1, pa);
            unsigned long long kk =
                ((unsigned long long)__float_as_uint(ov) << 32) |
                (unsigned long long)(0xFFFFFFFFu - (unsigned)p);
            if (kk > k[o]) k[o] = kk;
        }
    }
    for (int o = 0; o < O; ++o) {
        unsigned long long kk = k[o];
        for (int off = 32; off > 0; off >>= 1) {
            unsigned long long other = __shfl_down(kk, off, 64);
            if (other > kk) kk = other;
        }
        if (lane == 0) s_wk[wv][o] = kk;
    }
    __syncthreads();
    if (tid < O) {
        unsigned long long kk = s_wk[0][tid];
        for (int w = 1; w < TPB / 64; ++w)
            if (s_wk[w][tid] > kk) kk = s_wk[w][tid];
        pkeys[((size_t)b * O + tid) * S1 + chunk] = kk;
    }
}

// Stage 2 fused with conf loss. Grid B*CB, 256 priors per block.
// Reduces the S1 partial keys in LDS, does the per-prior sweep + forced
// override (last o wins, matching the reference scatter), then computes
// lse - gathered from LDS-staged conf rows. Plain per-block partial stores.
template <int ON, int CN>
__global__ __launch_bounds__(TPB) void match2_conf_kernel(
    const float* __restrict__ loc, const float* __restrict__ priors,
    const float* __restrict__ targets, const float* __restrict__ conf,
    const unsigned long long* __restrict__ pkeys,
    int P, int O_rt, int C_rt, int S1, int CB,
    float* __restrict__ mined, float* __restrict__ part_ll,
    float* __restrict__ part_pc, int* __restrict__ part_np) {
    constexpr int OMAX = (ON > 0) ? ON : 64;
    const int O = (ON > 0) ? ON : O_rt;
    const int C = (CN > 0) ? CN : C_rt;
    const int b = blockIdx.x / CB;
    const int chunk = blockIdx.x % CB;
    const int r0 = chunk * TPB;
    const int n = min(TPB, P - r0);
    const int tid = threadIdx.x;

    __shared__ float s_rows[TPB * ((CN > 0) ? CN : 32)];
    __shared__ float s_tx0[OMAX], s_ty0[OMAX], s_tx1[OMAX], s_ty1[OMAX];
    __shared__ float s_lab[OMAX], s_area[OMAX];
    __shared__ unsigned long long s_keys[OMAX];
    __shared__ int s_bp[OMAX];
    __shared__ float s_f[TPB], s_g[TPB];
    __shared__ int s_i[TPB];

    for (int o = tid; o < O; o += TPB) {
        const float* t = targets + ((size_t)b * O + o) * 5;
        float x0 = t[0], y0 = t[1], x1 = t[2], y1 = t[3];
        s_tx0[o] = x0; s_ty0[o] = y0; s_tx1[o] = x1; s_ty1[o] = y1;
        s_lab[o] = t[4];
        s_area[o] = (x1 - x0) * (y1 - y0);
        s_keys[o] = 0ull;
    }
    __syncthreads();

    // reduce partial keys (block-local LDS atomics — no contention issue)
    if (tid < O * S1) {
        int o = tid / S1, s = tid % S1;
        atomicMax(&s_keys[o], pkeys[((size_t)b * O + o) * S1 + s]);
    }
    // stage conf rows, coalesced float4
    {
        const float* g = conf + ((size_t)b * P + r0) * C;
        const int nf = n * C;
        if ((((size_t)g) & 15) == 0) {
            const int nf4 = nf >> 2;
            const float4* g4 = (const float4*)g;
            float4* s4 = (float4*)s_rows;
            for (int i = tid; i < nf4; i += TPB) s4[i] = g4[i];
            for (int i = (nf4 << 2) + tid; i < nf; i += TPB) s_rows[i] = g[i];
        } else {
            for (int i = tid; i < nf; i += TPB) s_rows[i] = g[i];
        }
    }
    __syncthreads();
    if (tid < O)
        s_bp[tid] = (int)(0xFFFFFFFFu - (unsigned)(s_keys[tid] & 0xFFFFFFFFull));
    __syncthreads();

    float ll = 0.0f, posc = 0.0f;
    int np = 0;
    if (tid < n) {
        const int p = r0 + tid;
        float4 pr = ((const float4*)priors)[p];
        float cx = pr.x, cy = pr.y, pw = pr.z, ph = pr.w;
        float px0 = cx - pw * 0.5f, py0 = cy - ph * 0.5f;
        float px1 = cx + pw * 0.5f, py1 = cy + ph * 0.5f;
        float pa = (px1 - px0) * (py1 - py0);
        float bto = -1.0f;
        int bti = 0;
        for (int o = 0; o < O; ++o) {
            float ov = jac(s_tx0[o], s_ty0[o], s_tx1[o], s_ty1[o], s_area[o],
                           px0, py0, px1, py1, pa);
            if (ov > bto) { bto = ov; bti = o; }  // first-max over o
        }
        for (int o = 0; o < O; ++o) {
            if (s_bp[o] == p) { bto = 2.0f; bti = o; }  // last o wins (ref scatter)
        }
        int c = (bto < 0.5f) ? 0 : ((int)s_lab[bti] + 1);

        const float* row = s_rows + tid * C;  // stride-21 LDS: 2-way alias, free
        float m = row[0];
        for (int j = 1; j < C; ++j) m = fmaxf(m, row[j]);
        float s = 0.0f;
        for (int j = 0; j < C; ++j) s += expf(row[j] - m);
        float lse = m + logf(s);
        float lc = lse - row[c];  // >= 0 always (s >= 1)
        bool pos = c > 0;
        mined[(size_t)b * P + p] = pos ? 0.0f : lc;
        if (pos) {
            posc = lc;
            np = 1;
            float mx0 = s_tx0[bti], my0 = s_ty0[bti], mx1 = s_tx1[bti], my1 = s_ty1[bti];
            float g0 = ((mx0 + mx1) * 0.5f - cx) / (0.1f * pw);
            float g1 = ((my0 + my1) * 0.5f - cy) / (0.1f * ph);
            float g2 = logf(fmaxf((mx1 - mx0) / pw, 1e-8f)) / 0.2f;
            float g3 = logf(fmaxf((my1 - my0) / ph, 1e-8f)) / 0.2f;
            float4 ld = ((const float4*)loc)[(size_t)b * P + p];
            float gt4[4] = {g0, g1, g2, g3};
            float lv[4] = {ld.x, ld.y, ld.z, ld.w};
#pragma unroll
            for (int j = 0; j < 4; ++j) {
                float d = lv[j] - gt4[j];
                float ad = fabsf(d);
                ll += (ad < 1.0f) ? 0.5f * d * d : (ad - 0.5f);
            }
        }
    }
    __syncthreads();
    s_f[tid] = ll; s_g[tid] = posc; s_i[tid] = np;
    __syncthreads();
    for (int s = TPB / 2; s > 0; s >>= 1) {
        if (tid < s) {
            s_f[tid] += s_f[tid + s];
            s_g[tid] += s_g[tid + s];
            s_i[tid] += s_i[tid + s];
        }
        __syncthreads();
    }
    if (tid == 0) {
        part_ll[blockIdx.x] = s_f[0];
        part_pc[blockIdx.x] = s_g[0];
        part_np[blockIdx.x] = s_i[0];
    }
}

// One 1024-thread block per batch. mined values register-cached (ONE global
// read instead of 5 sweeps). Radix-select k-th largest (values >= 0 so float
// bits are order-monotone): per-wave LDS histograms + log-step parallel
// suffix scan for the bin pick. sum(top-k) = sum_{>T} + (k - cnt_gt) * T;
// tie membership is value-identical so the sum is exact regardless of which
// tied indices the reference's stable argsort picks. Plain stores only.
__global__ __launch_bounds__(TPBS) void select_kernel(
    const float* __restrict__ mined, const float* __restrict__ part_ll,
    const float* __restrict__ part_pc, const int* __restrict__ part_np,
    float* __restrict__ ll_batch, float* __restrict__ lc_batch,
    int* __restrict__ np_batch, int P, int CB, int ratio) {
    const int b = blockIdx.x, tid = threadIdx.x;
    const int wv = tid >> 6;
    constexpr int W = TPBS / 64;
    const float* v = mined + (size_t)b * P;
    const int NIT = (P + TPBS - 1) / TPBS;
    const bool cached = (NIT <= RCAP);

    __shared__ float s_rs[TPBS];
    __shared__ int s_rc[TPBS];
    __shared__ int s_hist[W * 256];
    __shared__ int s_scan[257];
    __shared__ unsigned s_bsel;
    __shared__ int s_krn;

    // register-cache the batch row
    float rv[RCAP];
    if (cached) {
        for (int it = 0; it < NIT; ++it) {
            int p = tid + it * TPBS;
            rv[it] = (p < P) ? v[p] : 0.0f;
        }
    }

    // reduce per-chunk partials
    float pll = 0.0f, ppc = 0.0f;
    int pnp = 0;
    for (int i = tid; i < CB; i += TPBS) {
        pll += part_ll[b * CB + i];
        ppc += part_pc[b * CB + i];
        pnp += part_np[b * CB + i];
    }
    s_rs[tid] = pll; s_rc[tid] = pnp;
    __syncthreads();
    for (int s = TPBS / 2; s > 0; s >>= 1) {
        if (tid < s) { s_rs[tid] += s_rs[tid + s]; s_rc[tid] += s_rc[tid + s]; }
        __syncthreads();
    }
    const float ll_sum = s_rs[0];
    const int npos = s_rc[0];
    __syncthreads();
    s_rs[tid] = ppc;
    __syncthreads();
    for (int s = TPBS / 2; s > 0; s >>= 1) {
        if (tid < s) s_rs[tid] += s_rs[tid + s];
        __syncthreads();
    }
    const float sum_pos = s_rs[0];
    __syncthreads();

    const int k = min(ratio * npos, P - npos);
    if (tid == 0) {
        ll_batch[b] = ll_sum;
        np_batch[b] = npos;
    }
    if (k <= 0) {
        if (tid == 0) lc_batch[b] = sum_pos;
        return;
    }

    unsigned prefix = 0u;
    int kr = k;
    for (int pass = 0; pass < 4; ++pass) {
        const int shift = 24 - 8 * pass;
        const unsigned mask = (pass == 0) ? 0u : (0xFFFFFFFFu << (32 - 8 * pass));
        for (int i = tid; i < W * 256; i += TPBS) s_hist[i] = 0;
        __syncthreads();
        for (int it = 0; it < NIT; ++it) {
            int p = tid + it * TPBS;
            if (p < P) {
                unsigned u = __float_as_uint(cached ? rv[it] : v[p]);
                if ((u & mask) == prefix)
                    atomicAdd(&s_hist[wv * 256 + ((u >> shift) & 0xFF)], 1);
            }
        }
        __syncthreads();
        if (tid < 256) {
            int h = 0;
            for (int w = 0; w < W; ++w) h += s_hist[w * 256 + tid];
            s_scan[tid] = h;
        }
        if (tid == 0) s_scan[256] = 0;
        __syncthreads();
        // suffix-inclusive scan: s_scan[i] = sum_{j>=i} h[j]
        for (int d = 1; d < 256; d <<= 1) {
            int val = 0;
            if (tid < 256) val = s_scan[tid] + ((tid + d < 256) ? s_scan[tid + d] : 0);
            __syncthreads();
            if (tid < 256) s_scan[tid] = val;
            __syncthreads();
        }
        if (tid < 256) {
            int sge = s_scan[tid];
            int sgt = s_scan[tid + 1];
            if (sge >= kr && sgt < kr) {  // exactly one tid satisfies
                s_bsel = (unsigned)tid;
                s_krn = kr - sgt;
            }
        }
        __syncthreads();
        prefix |= s_bsel << shift;
        kr = s_krn;
        __syncthreads();
    }
    const float T = __uint_as_float(prefix);  // exact k-th largest value
    float lsum = 0.0f;
    int lcnt = 0;
    for (int it = 0; it < NIT; ++it) {
        int p = tid + it * TPBS;
        if (p < P) {
            float x = cached ? rv[it] : v[p];
            if (x > T) { lsum += x; ++lcnt; }
        }
    }
    s_rs[tid] = lsum; s_rc[tid] = lcnt;
    __syncthreads();
    for (int s = TPBS / 2; s > 0; s >>= 1) {
        if (tid < s) { s_rs[tid] += s_rs[tid + s]; s_rc[tid] += s_rc[tid + s]; }
        __syncthreads();
    }
    if (tid == 0) lc_batch[b] = sum_pos + s_rs[0] + (float)(k - s_rc[0]) * T;
}

__global__ __launch_bounds__(TPB) void finalize_kernel(
    const float* __restrict__ ll_batch, const int* __restrict__ np_batch,
    const float* __restrict__ lc_batch, int B, float* __restrict__ out) {
    const int tid = threadIdx.x;
    __shared__ float s_l[TPB], s_c[TPB];
    __shared__ int s_n[TPB];
    float l = 0.0f, c = 0.0f;
    int n = 0;
    for (int i = tid; i < B; i += TPB) {
        l += ll_batch[i];
        c += lc_batch[i];
        n += np_batch[i];
    }
    s_l[tid] = l; s_c[tid] = c; s_n[tid] = n;
    __syncthreads();
    for (int s = TPB / 2; s > 0; s >>= 1) {
        if (tid < s) {
            s_l[tid] += s_l[tid + s];
            s_c[tid] += s_c[tid + s];
            s_n[tid] += s_n[tid + s];
        }
        __syncthreads();
    }
    if (tid == 0) {
        float N = (float)s_n[0];
        out[0] = s_l[0] / N;
        out[1] = s_c[0] / N;
    }
}

extern "C" void kernel_launch(void* const* d_in, const int* in_sizes, int n_in,
                              void* d_out, int out_size, void* d_ws, size_t ws_size,
                              hipStream_t stream) {
    const float* loc = (const float*)d_in[0];
    const float* conf = (const float*)d_in[1];
    const float* priors = (const float*)d_in[2];
    const float* targets = (const float*)d_in[3];

    const int P = in_sizes[2] / 4;
    const int B = in_sizes[0] / (P * 4);
    const int C = in_sizes[1] / (in_sizes[0] / 4);  // conf / (B*P)
    const int O = in_sizes[3] / (B * 5);
    const size_t BP = (size_t)B * P;
    const int S1 = (P + CHP - 1) / CHP;   // match1 chunks per batch
    const int CB = (P + TPB - 1) / TPB;   // match2/conf chunks per batch

    // ws layout (8B-aligned first; everything fully written before read):
    unsigned long long* pkeys = (unsigned long long*)d_ws;  // B*O*S1 u64
    float* mined = (float*)(pkeys + (size_t)B * O * S1);    // BP f32
    float* part_ll = mined + BP;                            // B*CB f32
    float* part_pc = part_ll + (size_t)B * CB;              // B*CB f32
    int* part_np = (int*)(part_pc + (size_t)B * CB);        // B*CB i32
    float* ll_batch = (float*)(part_np + (size_t)B * CB);   // B f32
    float* lc_batch = ll_batch + B;                         // B f32
    int* np_batch = (int*)(lc_batch + B);                   // B i32

    if (O == 8) {
        match1_kernel<8><<<B * S1, TPB, 0, stream>>>(priors, targets, P, O, S1, pkeys);
        if (C == 21) {
            match2_conf_kernel<8, 21><<<B * CB, TPB, 0, stream>>>(
                loc, priors, targets, conf, pkeys, P, O, C, S1, CB,
                mined, part_ll, part_pc, part_np);
        } else {
            match2_conf_kernel<8, 0><<<B * CB, TPB, 0, stream>>>(
                loc, priors, targets, conf, pkeys, P, O, C, S1, CB,
                mined, part_ll, part_pc, part_np);
        }
    } else {
        match1_kernel<0><<<B * S1, TPB, 0, stream>>>(priors, targets, P, O, S1, pkeys);
        match2_conf_kernel<0, 0><<<B * CB, TPB, 0, stream>>>(
            loc, priors, targets, conf, pkeys, P, O, C, S1, CB,
            mined, part_ll, part_pc, part_np);
    }

    select_kernel<<<B, TPBS, 0, stream>>>(mined, part_ll, part_pc, part_np,
                                          ll_batch, lc_batch, np_batch, P, CB, 3);

    finalize_kernel<<<1, TPB, 0, stream>>>(ll_batch, np_batch, lc_batch, B,
                                           (float*)d_out);
}